// Round 2
// baseline (602.880 us; speedup 1.0000x reference)
//
#include <hip/hip_runtime.h>
#include <hip/hip_bf16.h>

typedef __bf16 bf16x8 __attribute__((ext_vector_type(8)));
typedef float f32x4 __attribute__((ext_vector_type(4)));
typedef unsigned short u16;
typedef unsigned int u32;
typedef u16 u16x8 __attribute__((ext_vector_type(8)));

#define DEV __device__ __forceinline__

DEV u16 f2b(float f) {
    u32 u = __builtin_bit_cast(u32, f);
    u32 r = (u + 0x7FFFu + ((u >> 16) & 1u)) >> 16;
    return (u16)r;
}
DEV float b2f(u16 b) {
    u32 u = ((u32)b) << 16;
    return __builtin_bit_cast(float, u);
}
DEV bf16x8 load8(const u16* p) {
    return __builtin_bit_cast(bf16x8, *(const uint4*)p);
}
DEV bf16x8 zero8() {
    uint4 z; z.x = 0; z.y = 0; z.z = 0; z.w = 0;
    return __builtin_bit_cast(bf16x8, z);
}
DEV bf16x8 cvt8(const float* f) {
    float fa[8];
    *(uint4*)fa = *(const uint4*)f;
    *(uint4*)(fa + 4) = *(const uint4*)(f + 4);
    u16x8 t;
    #pragma unroll
    for (int j = 0; j < 8; ++j) t[j] = f2b(fa[j]);
    return __builtin_bit_cast(bf16x8, t);
}
// MODE 0: buffer is bf16. MODE 1: buffer is fp32 (convert to bf16 on load).
template <int MODE>
DEV bf16x8 loadIn8(const void* p, long idx) {
    if constexpr (MODE == 0) return load8((const u16*)p + idx);
    else return cvt8((const float*)p + idx);
}

// ---------------- dtype detection: writes flag (0=bf16, 1=fp32) into ws
__global__ void detect_dtype(const u16* __restrict__ X, int* __restrict__ flag) {
    __shared__ int cnt;
    if (threadIdx.x == 0) cnt = 0;
    __syncthreads();
    float f = b2f(X[threadIdx.x]);
    float a = fabsf(f);
    int wild = (a > 1e4f) || (f != 0.f && a < 1e-20f) || (f != f);
    if (wild) atomicAdd(&cnt, 1);
    __syncthreads();
    if (threadIdx.x == 0) *flag = (cnt > 16) ? 1 : 0;
}

// ---------------- QKV projection: X[8192,640] @ W[640,640] -> [B,H,S,D] scatter
template <int MODE>
__global__ __launch_bounds__(256) void gemm_qkv(
    const int* __restrict__ flag,
    const void* __restrict__ X,
    const void* __restrict__ Wq, const void* __restrict__ Wk, const void* __restrict__ Wv,
    u16* __restrict__ q_ws, u16* __restrict__ k_ws, u16* __restrict__ v_ws)
{
    if (*flag != MODE) return;
    const int z = blockIdx.z;
    const void* W = (z == 0) ? Wq : ((z == 1) ? Wk : Wv);
    u16* dst = (z == 0) ? q_ws : ((z == 1) ? k_ws : v_ws);
    const int m0 = blockIdx.x * 64;
    const int n0 = blockIdx.y * 64;
    const int tid = threadIdx.x;
    const int lane = tid & 63;
    const int w = tid >> 6;
    const int wm = w >> 1, wn = w & 1;
    const int lg = lane >> 4, lr = lane & 15;

    __shared__ u16 Wt[64][72];   // W^T tile: [n][k]

    f32x4 acc[2][2] = {};
    for (int kt0 = 0; kt0 < 640; kt0 += 64) {
        // stage W[kt0..+64][n0..+64] transposed
        {
            int kk = tid >> 2;
            int nc = (tid & 3) * 16;
            long base = (long)(kt0 + kk) * 640 + n0 + nc;
            u16x8 a = __builtin_bit_cast(u16x8, loadIn8<MODE>(W, base));
            u16x8 b = __builtin_bit_cast(u16x8, loadIn8<MODE>(W, base + 8));
            #pragma unroll
            for (int j = 0; j < 8; ++j) {
                Wt[nc + j][kk] = a[j];
                Wt[nc + 8 + j][kk] = b[j];
            }
        }
        __syncthreads();
        #pragma unroll
        for (int ks = 0; ks < 64; ks += 32) {
            bf16x8 a[2], b[2];
            #pragma unroll
            for (int mi = 0; mi < 2; ++mi) {
                int row = m0 + wm * 32 + mi * 16 + lr;
                int k = kt0 + ks + lg * 8;
                a[mi] = loadIn8<MODE>(X, (long)row * 640 + k);
            }
            #pragma unroll
            for (int ni = 0; ni < 2; ++ni) {
                int n = wn * 32 + ni * 16 + lr;
                b[ni] = load8(&Wt[n][ks + lg * 8]);
            }
            #pragma unroll
            for (int mi = 0; mi < 2; ++mi)
                #pragma unroll
                for (int ni = 0; ni < 2; ++ni)
                    acc[mi][ni] = __builtin_amdgcn_mfma_f32_16x16x32_bf16(a[mi], b[ni], acc[mi][ni], 0, 0, 0);
        }
        __syncthreads();
    }
    #pragma unroll
    for (int mi = 0; mi < 2; ++mi)
        #pragma unroll
        for (int ni = 0; ni < 2; ++ni)
            #pragma unroll
            for (int r = 0; r < 4; ++r) {
                int m = m0 + wm * 32 + mi * 16 + lg * 4 + r;
                int n = n0 + wn * 32 + ni * 16 + lr;
                int b_ = m >> 12, s = m & 4095;
                int h = n / 80, d = n % 80;
                dst[(((long)b_ * 8 + h) * 4096 + s) * 80 + d] = f2b(acc[mi][ni][r]);
            }
}

// ---------------- Flash attention: per block one (b,h) x 64 Q-rows (bf16 ws only)
__global__ __launch_bounds__(256) void attn(
    const u16* __restrict__ q_ws, const u16* __restrict__ k_ws,
    const u16* __restrict__ v_ws, u16* __restrict__ o_ws)
{
    const int bh = blockIdx.y;
    const int qb = blockIdx.x * 64;
    const int tid = threadIdx.x;
    const int lane = tid & 63;
    const int w = tid >> 6;
    const int lg = lane >> 4, lr = lane & 15;
    const float scale = 0.11180339887498949f; // 1/sqrt(80)

    __shared__ u16 Vt[80][72];  // V^T tile: [d][kv]
    __shared__ u16 P[64][72];   // probs bf16: [q][kv]

    bf16x8 qf[3];
    #pragma unroll
    for (int kt = 0; kt < 3; ++kt) {
        int k = kt * 32 + lg * 8;
        int row = qb + w * 16 + lr;
        qf[kt] = (k < 80) ? load8(q_ws + ((long)bh * 4096 + row) * 80 + k) : zero8();
    }

    float m_run[4], l_run[4];
    #pragma unroll
    for (int r = 0; r < 4; ++r) { m_run[r] = -1e30f; l_run[r] = 0.f; }
    f32x4 acc[5] = {};

    for (int kv0 = 0; kv0 < 4096; kv0 += 64) {
        #pragma unroll
        for (int i = 0; i < 5; ++i) {
            int e4 = (i * 256 + tid) * 4;
            int kk = e4 / 80;
            int d0 = e4 % 80;
            const u16* src = v_ws + ((long)bh * 4096 + kv0 + kk) * 80 + d0;
            u16 tmp[4];
            *(uint2*)tmp = *(const uint2*)src;
            #pragma unroll
            for (int j = 0; j < 4; ++j) Vt[d0 + j][kk] = tmp[j];
        }
        f32x4 sf[4] = {};
        #pragma unroll
        for (int nt = 0; nt < 4; ++nt) {
            const u16* kp = k_ws + ((long)bh * 4096 + kv0 + nt * 16 + lr) * 80;
            #pragma unroll
            for (int kt = 0; kt < 3; ++kt) {
                int k = kt * 32 + lg * 8;
                bf16x8 kf = (k < 80) ? load8(kp + k) : zero8();
                sf[nt] = __builtin_amdgcn_mfma_f32_16x16x32_bf16(qf[kt], kf, sf[nt], 0, 0, 0);
            }
        }
        #pragma unroll
        for (int r = 0; r < 4; ++r) {
            float s0 = sf[0][r] * scale, s1 = sf[1][r] * scale;
            float s2 = sf[2][r] * scale, s3 = sf[3][r] * scale;
            float rmax = fmaxf(fmaxf(s0, s1), fmaxf(s2, s3));
            rmax = fmaxf(rmax, __shfl_xor(rmax, 1));
            rmax = fmaxf(rmax, __shfl_xor(rmax, 2));
            rmax = fmaxf(rmax, __shfl_xor(rmax, 4));
            rmax = fmaxf(rmax, __shfl_xor(rmax, 8));
            float mnew = fmaxf(m_run[r], rmax);
            float alpha = __expf(m_run[r] - mnew);
            m_run[r] = mnew;
            float p0 = __expf(s0 - mnew), p1 = __expf(s1 - mnew);
            float p2 = __expf(s2 - mnew), p3 = __expf(s3 - mnew);
            int prow = w * 16 + lg * 4 + r;
            P[prow][0 * 16 + lr] = f2b(p0);
            P[prow][1 * 16 + lr] = f2b(p1);
            P[prow][2 * 16 + lr] = f2b(p2);
            P[prow][3 * 16 + lr] = f2b(p3);
            float ps = p0 + p1 + p2 + p3;
            ps += __shfl_xor(ps, 1);
            ps += __shfl_xor(ps, 2);
            ps += __shfl_xor(ps, 4);
            ps += __shfl_xor(ps, 8);
            l_run[r] = l_run[r] * alpha + ps;
            #pragma unroll
            for (int dt = 0; dt < 5; ++dt) acc[dt][r] *= alpha;
        }
        __syncthreads();
        bf16x8 pa[2];
        #pragma unroll
        for (int kt = 0; kt < 2; ++kt)
            pa[kt] = load8(&P[w * 16 + lr][kt * 32 + lg * 8]);
        #pragma unroll
        for (int dt = 0; dt < 5; ++dt) {
            #pragma unroll
            for (int kt = 0; kt < 2; ++kt) {
                bf16x8 vb = load8(&Vt[dt * 16 + lr][kt * 32 + lg * 8]);
                acc[dt] = __builtin_amdgcn_mfma_f32_16x16x32_bf16(pa[kt], vb, acc[dt], 0, 0, 0);
            }
        }
        __syncthreads();
    }
    int b_ = bh >> 3, h = bh & 7;
    #pragma unroll
    for (int dt = 0; dt < 5; ++dt)
        #pragma unroll
        for (int r = 0; r < 4; ++r) {
            int row = qb + w * 16 + lg * 4 + r;
            int col = h * 80 + dt * 16 + lr;
            o_ws[((long)b_ * 4096 + row) * 640 + col] = f2b(acc[dt][r] / l_run[r]);
        }
}

// ---------------- Output projection: O[8192,640] @ Wo + bo -> d_out
template <int MODE>
__global__ __launch_bounds__(256) void gemm_out(
    const int* __restrict__ flag,
    const u16* __restrict__ X, const void* __restrict__ W,
    const void* __restrict__ bias, void* __restrict__ out)
{
    if (*flag != MODE) return;
    const int m0 = blockIdx.x * 64;
    const int n0 = blockIdx.y * 64;
    const int tid = threadIdx.x;
    const int lane = tid & 63;
    const int w = tid >> 6;
    const int wm = w >> 1, wn = w & 1;
    const int lg = lane >> 4, lr = lane & 15;

    __shared__ u16 Wt[64][72];

    f32x4 acc[2][2] = {};
    for (int kt0 = 0; kt0 < 640; kt0 += 64) {
        {
            int kk = tid >> 2;
            int nc = (tid & 3) * 16;
            long base = (long)(kt0 + kk) * 640 + n0 + nc;
            u16x8 a = __builtin_bit_cast(u16x8, loadIn8<MODE>(W, base));
            u16x8 b = __builtin_bit_cast(u16x8, loadIn8<MODE>(W, base + 8));
            #pragma unroll
            for (int j = 0; j < 8; ++j) {
                Wt[nc + j][kk] = a[j];
                Wt[nc + 8 + j][kk] = b[j];
            }
        }
        __syncthreads();
        #pragma unroll
        for (int ks = 0; ks < 64; ks += 32) {
            bf16x8 a[2], b[2];
            #pragma unroll
            for (int mi = 0; mi < 2; ++mi) {
                int row = m0 + wm * 32 + mi * 16 + lr;
                int k = kt0 + ks + lg * 8;
                a[mi] = load8(X + (long)row * 640 + k);
            }
            #pragma unroll
            for (int ni = 0; ni < 2; ++ni) {
                int n = wn * 32 + ni * 16 + lr;
                b[ni] = load8(&Wt[n][ks + lg * 8]);
            }
            #pragma unroll
            for (int mi = 0; mi < 2; ++mi)
                #pragma unroll
                for (int ni = 0; ni < 2; ++ni)
                    acc[mi][ni] = __builtin_amdgcn_mfma_f32_16x16x32_bf16(a[mi], b[ni], acc[mi][ni], 0, 0, 0);
        }
        __syncthreads();
    }
    #pragma unroll
    for (int mi = 0; mi < 2; ++mi)
        #pragma unroll
        for (int ni = 0; ni < 2; ++ni)
            #pragma unroll
            for (int r = 0; r < 4; ++r) {
                int m = m0 + wm * 32 + mi * 16 + lg * 4 + r;
                int n = n0 + wn * 32 + ni * 16 + lr;
                float bv = (MODE == 0) ? b2f(((const u16*)bias)[n]) : ((const float*)bias)[n];
                float v = acc[mi][ni][r] + bv;
                if constexpr (MODE == 0) ((u16*)out)[(long)m * 640 + n] = f2b(v);
                else ((float*)out)[(long)m * 640 + n] = v;
            }
}

extern "C" void kernel_launch(void* const* d_in, const int* in_sizes, int n_in,
                              void* d_out, int out_size, void* d_ws, size_t ws_size,
                              hipStream_t stream) {
    const void* x  = d_in[0];
    const void* Wq = d_in[1];
    const void* Wk = d_in[2];
    const void* Wv = d_in[3];
    const void* Wo = d_in[4];
    const void* bo = d_in[5];

    int* flag = (int*)d_ws;
    u16* ws = (u16*)d_ws + 16;
    const size_t SZ = 16u * 4096u * 80u; // 5,242,880 elems (= 8192*640)
    u16* q_ws = ws;
    u16* k_ws = ws + SZ;
    u16* v_ws = ws + 2 * SZ;
    u16* o_ws = ws + 3 * SZ;

    detect_dtype<<<1, 256, 0, stream>>>((const u16*)x, flag);

    dim3 g1(128, 10, 3);
    gemm_qkv<0><<<g1, 256, 0, stream>>>(flag, x, Wq, Wk, Wv, q_ws, k_ws, v_ws);
    gemm_qkv<1><<<g1, 256, 0, stream>>>(flag, x, Wq, Wk, Wv, q_ws, k_ws, v_ws);

    dim3 g2(64, 16);
    attn<<<g2, 256, 0, stream>>>(q_ws, k_ws, v_ws, o_ws);

    dim3 g3(128, 10);
    gemm_out<0><<<g3, 256, 0, stream>>>(flag, o_ws, Wo, bo, d_out);
    gemm_out<1><<<g3, 256, 0, stream>>>(flag, o_ws, Wo, bo, d_out);
}